// Round 2
// baseline (155.851 us; speedup 1.0000x reference)
//
#include <hip/hip_runtime.h>
#include <math.h>

#define SIMG 128
#define NPIX (SIMG*SIMG)
#define MAXCHUNK 20

// ((a0*b0 + a1*b1) + a2*b2) with strict per-op fp32 rounding (matches numpy einsum order)
__device__ __forceinline__ float dot3_rn(float a0,float a1,float a2,float b0,float b1,float b2){
  return __fadd_rn(__fadd_rn(__fmul_rn(a0,b0),__fmul_rn(a1,b1)),__fmul_rn(a2,b2));
}

// Per-face record: 20 floats (80 B, 16B-aligned):
// [0..3]  bxmin,bxmax,bymin,bymax   (conservative NDC bbox, +-1e-4 slop)
// [4..9]  x0,y0,x1,y1,x2,y2         (projected NDC coords)
// [10..12] z0,z1,z2                 (camera z)
// [13..18] e0x,e0y,e1x,e1y,e2x,e2y  (edge deltas, precomputed with same rounding as ref)
// [19]    pad
__global__ void k_face_setup(const float* __restrict__ verts, const int* __restrict__ faces,
                             const float* __restrict__ tex,
                             const float* __restrict__ Rm, const float* __restrict__ tv,
                             const float* __restrict__ Km,
                             const float* __restrict__ ldir,
                             const float* __restrict__ idir, const float* __restrict__ iamb,
                             float* __restrict__ frec, float* __restrict__ fcol, int F)
{
  int f = blockIdx.x*blockDim.x + threadIdx.x;
  if (f >= F) return;
  int idx[3];
  idx[0] = faces[3*f+0]; idx[1] = faces[3*f+1]; idx[2] = faces[3*f+2];
  float P[3][3];
  float uu[3], vv2[3], zz[3];
  #pragma unroll
  for (int k=0;k<3;k++){
    float X = verts[3*idx[k]+0], Y = verts[3*idx[k]+1], Z = verts[3*idx[k]+2];
    P[k][0]=X; P[k][1]=Y; P[k][2]=Z;
    // v = einsum('bnj,bij->bni', vertices, R) + t   (sum order j=0,1,2)
    float cx = __fadd_rn(dot3_rn(X,Y,Z, Rm[0],Rm[1],Rm[2]), tv[0]);
    float cy = __fadd_rn(dot3_rn(X,Y,Z, Rm[3],Rm[4],Rm[5]), tv[1]);
    float cz = __fadd_rn(dot3_rn(X,Y,Z, Rm[6],Rm[7],Rm[8]), tv[2]);
    float zd = __fadd_rn(cz, 1e-9f);
    float x_ = __fdiv_rn(cx, zd);
    float y_ = __fdiv_rn(cy, zd);
    // uvw = einsum('bnj,ij->bni', [x_,y_,1], K); h2*K[i][2] == K[i][2] exactly
    float ur = __fadd_rn(__fadd_rn(__fmul_rn(x_,Km[0]),__fmul_rn(y_,Km[1])), Km[2]);
    float vr = __fadd_rn(__fadd_rn(__fmul_rn(x_,Km[3]),__fmul_rn(y_,Km[4])), Km[5]);
    float vflip = __fsub_rn(128.0f, vr);                 // orig_size - uvw[...,1]
    uu[k]  = __fdiv_rn(__fmul_rn(2.0f, __fsub_rn(ur,   64.0f)), 128.0f);
    vv2[k] = __fdiv_rn(__fmul_rn(2.0f, __fsub_rn(vflip,64.0f)), 128.0f);
    zz[k]  = cz;
  }
  float x0=uu[0], y0=vv2[0], x1=uu[1], y1=vv2[1], x2=uu[2], y2=vv2[2];
  // edge deltas exactly as reference: ex = b.x - a.x etc.
  float e0x=__fsub_rn(x2,x1), e0y=__fsub_rn(y2,y1);   // edge(v1,v2)
  float e1x=__fsub_rn(x0,x2), e1y=__fsub_rn(y0,y2);   // edge(v2,v0)
  float e2x=__fsub_rn(x1,x0), e2y=__fsub_rn(y1,y0);   // edge(v0,v1)
  // conservative bbox (NaN -> comparisons in raster fall through to full test)
  float bxmin = fminf(fminf(x0,x1),x2) - 1e-4f;
  float bxmax = fmaxf(fmaxf(x0,x1),x2) + 1e-4f;
  float bymin = fminf(fminf(y0,y1),y2) - 1e-4f;
  float bymax = fmaxf(fmaxf(y0,y1),y2) + 1e-4f;
  float* r = frec + (size_t)f*20;
  r[0]=bxmin; r[1]=bxmax; r[2]=bymin; r[3]=bymax;
  r[4]=x0; r[5]=y0; r[6]=x1; r[7]=y1;
  r[8]=x2; r[9]=y2; r[10]=zz[0]; r[11]=zz[1];
  r[12]=zz[2]; r[13]=e0x; r[14]=e0y; r[15]=e1x;
  r[16]=e1y; r[17]=e2x; r[18]=e2y; r[19]=0.0f;

  // lighting: n = cross(p0-p1, p2-p1), normalize, cos=relu(dot(n,dir))
  float ax=__fsub_rn(P[0][0],P[1][0]), ay=__fsub_rn(P[0][1],P[1][1]), az=__fsub_rn(P[0][2],P[1][2]);
  float bx=__fsub_rn(P[2][0],P[1][0]), by=__fsub_rn(P[2][1],P[1][1]), bz=__fsub_rn(P[2][2],P[1][2]);
  float nx=__fsub_rn(__fmul_rn(ay,bz),__fmul_rn(az,by));
  float ny=__fsub_rn(__fmul_rn(az,bx),__fmul_rn(ax,bz));
  float nz=__fsub_rn(__fmul_rn(ax,by),__fmul_rn(ay,bx));
  float nn=__fsqrt_rn(dot3_rn(nx,ny,nz,nx,ny,nz));
  nn = fmaxf(nn, 1e-5f);
  nx=__fdiv_rn(nx,nn); ny=__fdiv_rn(ny,nn); nz=__fdiv_rn(nz,nn);
  float cosv = fmaxf(0.0f, dot3_rn(nx,ny,nz, ldir[0],ldir[1],ldir[2]));
  float light = __fadd_rn(iamb[0], __fmul_rn(idir[0], cosv));
  fcol[3*f+0]=__fmul_rn(tex[3*f+0], light);
  fcol[3*f+1]=__fmul_rn(tex[3*f+1], light);
  fcol[3*f+2]=__fmul_rn(tex[3*f+2], light);
}

// grid: (64 tiles of 16x16, nchunk face chunks); block: 256 threads (1 pixel each)
__global__ void k_raster(const float* __restrict__ frec,
                         float* __restrict__ pd, int* __restrict__ pi,
                         int F, int CF)
{
  int tile  = blockIdx.x;
  int chunk = blockIdx.y;
  int tx = threadIdx.x & 15, ty = threadIdx.x >> 4;
  int x = ((tile & 7) << 4) + tx;
  int y = ((tile >> 3) << 4) + ty;
  float px = (float)(2*x + 1 - SIMG) / 128.0f;   // exact
  float py = (float)(2*y + 1 - SIMG) / 128.0f;   // exact
  // tile pixel-center bounds (for bbox rejection)
  int bx0 = (tile & 7) << 4, by0 = (tile >> 3) << 4;
  float tpx0 = (float)(2*bx0      + 1 - SIMG) / 128.0f;
  float tpx1 = (float)(2*(bx0+15) + 1 - SIMG) / 128.0f;
  float tpy0 = (float)(2*by0      + 1 - SIMG) / 128.0f;
  float tpy1 = (float)(2*(by0+15) + 1 - SIMG) / 128.0f;

  int f0 = chunk*CF;
  int f1 = min(F, f0 + CF);
  float bestd = __builtin_inff();
  int   besti = 0;
  for (int f = f0; f < f1; ++f) {
    const float4* rp = (const float4*)(frec + (size_t)f*20);
    float4 r0 = rp[0];   // bbox
    // skip if tile definitely outside bbox (NaN-safe: NaN -> all false -> no skip)
    if (r0.y < tpx0 || r0.x > tpx1 || r0.w < tpy0 || r0.z > tpy1) continue;
    float4 r1 = rp[1], r2 = rp[2], r3 = rp[3], r4 = rp[4];
    float x0=r1.x, y0=r1.y, x1=r1.z, y1=r1.w;
    float x2=r2.x, y2=r2.y, z0=r2.z, z1=r2.w;
    float z2=r3.x, e0x=r3.y, e0y=r3.z, e1x=r3.w;
    float e1y=r4.x, e2x=r4.y, e2y=r4.z;
    // w = ex*(py-ay) - ey*(px-ax), strict per-op rounding (no FMA)
    float w0 = __fsub_rn(__fmul_rn(e0x,__fsub_rn(py,y1)), __fmul_rn(e0y,__fsub_rn(px,x1)));
    float w1 = __fsub_rn(__fmul_rn(e1x,__fsub_rn(py,y2)), __fmul_rn(e1y,__fsub_rn(px,x2)));
    float w2 = __fsub_rn(__fmul_rn(e2x,__fsub_rn(py,y0)), __fmul_rn(e2y,__fsub_rn(px,x0)));
    float area = __fadd_rn(__fadd_rn(w0,w1),w2);
    bool sgn = (w0>=0.0f && w1>=0.0f && w2>=0.0f) || (w0<=0.0f && w1<=0.0f && w2<=0.0f);
    bool okf = fabsf(area) > 1e-10f;
    if (sgn && okf) {
      float inv = __fdiv_rn(1.0f, area);
      float q0 = __fdiv_rn(__fmul_rn(w0,inv), z0);
      float q1 = __fdiv_rn(__fmul_rn(w1,inv), z1);
      float q2 = __fdiv_rn(__fmul_rn(w2,inv), z2);
      float den = __fadd_rn(__fadd_rn(__fadd_rn(q0,q1),q2), 1e-12f);
      float zp = __fdiv_rn(1.0f, den);
      if (zp > 0.1f && zp < 100.0f && zp < bestd) { bestd = zp; besti = f; }
    }
  }
  int pix = y*SIMG + x;
  pd[(size_t)chunk*NPIX + pix] = bestd;
  pi[(size_t)chunk*NPIX + pix] = besti;
}

__global__ void k_resolve(const float* __restrict__ pd, const int* __restrict__ pi,
                          const float* __restrict__ fcol,
                          float* __restrict__ out_rgb, float* __restrict__ gray,
                          int nchunk)
{
  int pix = blockIdx.x*blockDim.x + threadIdx.x;
  float bestd = __builtin_inff();
  int   besti = 0;
  // chunks in increasing face order; strict < keeps first (lowest-index) min -> argmin semantics
  for (int c = 0; c < nchunk; ++c) {
    float d = pd[(size_t)c*NPIX + pix];
    int   i = pi[(size_t)c*NPIX + pix];
    if (d < bestd) { bestd = d; besti = i; }
  }
  bool hit = bestd < 1e30f;
  float c0=0.0f, c1=0.0f, c2=0.0f;
  if (hit) { c0 = fcol[3*besti+0]; c1 = fcol[3*besti+1]; c2 = fcol[3*besti+2]; }
  out_rgb[pix]          = c0;
  out_rgb[NPIX + pix]   = c1;
  out_rgb[2*NPIX + pix] = c2;
  gray[pix] = __fadd_rn(__fadd_rn(c0,c1),c2);   // channel sum, same order as np
}

__global__ void k_max(const float* __restrict__ gray, float* __restrict__ gmax)
{
  float m = -__builtin_inff();
  for (int i = threadIdx.x; i < NPIX; i += 1024) m = fmaxf(m, gray[i]);
  #pragma unroll
  for (int off = 32; off > 0; off >>= 1) m = fmaxf(m, __shfl_down(m, off, 64));
  __shared__ float sm[16];
  if ((threadIdx.x & 63) == 0) sm[threadIdx.x >> 6] = m;
  __syncthreads();
  if (threadIdx.x < 16) {
    m = sm[threadIdx.x];
    #pragma unroll
    for (int off = 8; off > 0; off >>= 1) m = fmaxf(m, __shfl_down(m, off, 16));
    if (threadIdx.x == 0) gmax[0] = m;
  }
}

__global__ void k_loss(const float* __restrict__ gray, const float* __restrict__ gmax,
                       const float* __restrict__ mimg, const float* __restrict__ mask,
                       float* __restrict__ out)
{
  float mx = gmax[0];
  float ssum = 0.0f, msum = 0.0f;
  for (int i = threadIdx.x; i < NPIX; i += 1024) {
    float g = __fdiv_rn(gray[i], mx);
    float d = __fsub_rn(g, mimg[i]);
    ssum = __fadd_rn(ssum, __fmul_rn(d,d));
    msum = __fadd_rn(msum, mask[i]);
  }
  #pragma unroll
  for (int off = 32; off > 0; off >>= 1) {
    ssum += __shfl_down(ssum, off, 64);
    msum += __shfl_down(msum, off, 64);
  }
  __shared__ float s1[16], s2[16];
  if ((threadIdx.x & 63) == 0) { s1[threadIdx.x>>6] = ssum; s2[threadIdx.x>>6] = msum; }
  __syncthreads();
  if (threadIdx.x < 16) {
    ssum = s1[threadIdx.x]; msum = s2[threadIdx.x];
    #pragma unroll
    for (int off = 8; off > 0; off >>= 1) {
      ssum += __shfl_down(ssum, off, 16);
      msum += __shfl_down(msum, off, 16);
    }
    if (threadIdx.x == 0) out[0] = __fdiv_rn(ssum, msum);
  }
}

extern "C" void kernel_launch(void* const* d_in, const int* in_sizes, int n_in,
                              void* d_out, int out_size, void* d_ws, size_t ws_size,
                              hipStream_t stream)
{
  const float* verts = (const float*)d_in[0];
  const int*   faces = (const int*)  d_in[1];
  const float* tex   = (const float*)d_in[2];
  const float* Rm    = (const float*)d_in[3];
  const float* tv    = (const float*)d_in[4];
  const float* Km    = (const float*)d_in[5];
  const float* mimg  = (const float*)d_in[6];
  const float* mask  = (const float*)d_in[7];
  const float* ldir  = (const float*)d_in[8];
  const float* idir  = (const float*)d_in[9];
  const float* iamb  = (const float*)d_in[10];
  int F = in_sizes[1] / 3;

  // Workspace layout (floats), sized defensively against ws_size.
  // fixed: frec F*20 + fcol F*3 + gray NPIX + gmax 64 (padding)
  size_t fixed_floats = (size_t)F*20 + (size_t)F*3 + NPIX + 64;
  size_t avail_floats = ws_size / 4;
  int nchunk = 1;
  if (avail_floats > fixed_floats) {
    size_t per_chunk = (size_t)NPIX * 2;     // pd + pi (4B each)
    size_t c = (avail_floats - fixed_floats) / per_chunk;
    nchunk = (int)(c < 1 ? 1 : (c > MAXCHUNK ? MAXCHUNK : c));
  }
  int CF = (F + nchunk - 1) / nchunk;

  float* ws   = (float*)d_ws;
  float* frec = ws;                               // F*20 floats
  float* fcol = frec + (size_t)F*20;              // F*3
  float* gray = fcol + (size_t)F*3;               // NPIX
  float* gmax = gray + NPIX;                      // 1 (+63 pad)
  float* pd   = gmax + 64;                        // nchunk*NPIX
  int*   pi   = (int*)(pd + (size_t)nchunk*NPIX); // nchunk*NPIX
  float* out  = (float*)d_out;

  hipLaunchKernelGGL(k_face_setup, dim3((F+255)/256), dim3(256), 0, stream,
                     verts, faces, tex, Rm, tv, Km, ldir, idir, iamb, frec, fcol, F);
  hipLaunchKernelGGL(k_raster, dim3(64, nchunk), dim3(256), 0, stream,
                     frec, pd, pi, F, CF);
  hipLaunchKernelGGL(k_resolve, dim3(64), dim3(256), 0, stream,
                     pd, pi, fcol, out + 1, gray, nchunk);
  hipLaunchKernelGGL(k_max, dim3(1), dim3(1024), 0, stream, gray, gmax);
  hipLaunchKernelGGL(k_loss, dim3(1), dim3(1024), 0, stream, gray, gmax, mimg, mask, out);
}